// Round 14
// baseline (117.335 us; speedup 1.0000x reference)
//
#include <hip/hip_runtime.h>
#include <math.h>

// SLAYER MLP forward: spike(psp(W2 @ spike(psp(W1 @ x))))
// B=256, IN=78, HID=16, OUT=20, T=1000, K=100 (SRM alpha, tau=10)
//
// fp64 accumulation everywhere (absmax 0.0 rounds 0-13), fp32 rounding at
// reference materialization points (einsum outputs z1/z2, final u).
//
// Round-14: FIR restructured to 4 outputs/thread (was 8). Round 13 measured
// fm at VGPR=104 -> 4 waves/SIMD cap, 17% occupancy, 38% VALUBusy: the
// 8-output FIR's 12-double window + 8 accs keeps liveness > 64 VGPR, and
// launch_bounds caps provably spill (rounds 6/12). 4-output FIR: 2-quad
// window, period-2 rotation, 4 accs -> ~55 VGPR live -> 8 waves/SIMD without
// caps. Same math (taps 4g..4g+3, u[d] += eps[4g+e]*V[3+d-e]). Applied to
// fm phase 1 and fir_g. mm1 / mm2-phase / launcher unchanged.

#define B_     256
#define IN_    78
#define HID_   16
#define OUT_   20
#define T_     1000
#define TT_    125
#define J_     224              // TT + K - 1
#define ZSTR_  228              // fir LDS row stride (floats)
#define TC_    128              // mm1 t-chunk
#define MSTR_  132              // mm1 LDS row stride (floats)

#define LOADF(X0,X1,X2,X3, P) { \
  const float4 lf_ = *(const float4*)(P); \
  X0 = (double)lf_.x; X1 = (double)lf_.y; X2 = (double)lf_.z; X3 = (double)lf_.w; }

// 4-output FIR group: taps eps[4g..4g+3]; window V[0..6] = {N0..N3, P0..P2}
// (N = quad 24-g, P = low 3 of quad 25-g). u[d] += eps[4g+e] * V[3+d-e].
#define GRP4(EP, N0,N1,N2,N3, P0,P1,P2) { \
  const double2 e01_ = *(const double2*)(EP); \
  const double2 e23_ = *(const double2*)((EP)+2); \
  u0 += e01_.x*(N3); u1 += e01_.x*(P0); u2 += e01_.x*(P1); u3 += e01_.x*(P2); \
  u0 += e01_.y*(N2); u1 += e01_.y*(N3); u2 += e01_.y*(P0); u3 += e01_.y*(P1); \
  u0 += e23_.x*(N1); u1 += e23_.x*(N2); u2 += e23_.x*(N3); u3 += e23_.x*(P0); \
  u0 += e23_.y*(N0); u1 += e23_.y*(N1); u2 += e23_.y*(N2); u3 += e23_.y*(N3); }

// Rolled 4-output FIR over one zf row slice (ZROW4 = row + 4*q8).
// 25 groups: group 0 + 12 iterations x 2 (period-2 A/B rotation).
// Expects eps_d, u0..u3 in scope.
#define FIR4_BODY(ZROW4) { \
  double A0,A1,A2,A3,B0,B1,B2,B3; \
  LOADF(A0,A1,A2,A3, (ZROW4) + 96); \
  LOADF(B0,B1,B2,B3, (ZROW4) + 100); \
  GRP4(eps_d, A0,A1,A2,A3, B0,B1,B2) \
  const float*  zp_ = (ZROW4) + 92; \
  const double* ep_ = eps_d + 4; \
  _Pragma("unroll 1") \
  for (int k_ = 0; k_ < 12; ++k_) { \
    LOADF(B0,B1,B2,B3, zp_); \
    GRP4(ep_,     B0,B1,B2,B3, A0,A1,A2) \
    LOADF(A0,A1,A2,A3, zp_ - 4); \
    GRP4(ep_ + 4, A0,A1,A2,A3, B0,B1,B2) \
    zp_ -= 8; ep_ += 8; \
  } }

__device__ __forceinline__ void init_eps_d(double* eps_d, int tid) {
  if (tid < 100) {
    float a = (float)tid / 10.0f;           // identical fp32 ops to reference
    float e = a * expf(1.0f - a);
    eps_d[tid] = (double)e;                 // exact widening
  }
}

// ---------------- mm building blocks --------------------------------------
#define MMROW2(XR, W0, W1) { \
  const float2 f0_ = *(const float2*)(XR); \
  const float2 f1_ = *(const float2*)((XR) + 64); \
  const double x0_=(double)f0_.x, x1_=(double)f0_.y; \
  const double x2_=(double)f1_.x, x3_=(double)f1_.y; \
  m00 += (W0)*x0_; m01 += (W0)*x1_; m02 += (W0)*x2_; m03 += (W0)*x3_; \
  m10 += (W1)*x0_; m11 += (W1)*x1_; m12 += (W1)*x2_; m13 += (W1)*x3_; }

#define STORE2(BASE, EOFF, MA, MB) \
  if (tb + (EOFF) < T_ - 1) \
    *(float2*)&zout[(BASE) + (size_t)(tb + (EOFF))] = \
        make_float2((float)(MA), (float)(MB));

// -------- mm1: z1[b,h,t] = sum_i W1[h,i] * x[b,i,t]  (round-9 verbatim) ----
__global__ __launch_bounds__(256) void mm1(
    const float* __restrict__ x, const float* __restrict__ W1,
    float* __restrict__ zout)
{
  __shared__ float  xs[13 * MSTR_];   // 6,864 B
  __shared__ double wd[16 * 80];      // 10,240 B

  const int tid = threadIdx.x;
  const int b   = blockIdx.x >> 3;
  const int tc  = blockIdx.x & 7;
  const int tcb = tc * TC_;

  for (int idx = tid; idx < HID_ * IN_; idx += 256)
    wd[(idx / IN_) * 80 + (idx % IN_)] = (double)W1[idx];

  const int  c_  = tid & 127;
  const int  r0_ = tid >> 7;          // 0 or 1
  const int  tg_ = tcb + c_;
  const bool tok = (tg_ < T_);
  const bool t6  = tok && (r0_ == 0); // row 12 exists only for r0=0

  const int p = tid >> 5;
  const int q = tid & 31;

  double m00=0,m01=0,m02=0,m03=0,m10=0,m11=0,m12=0,m13=0;
  float g0,g1,g2,g3,g4,g5,g6;

#define ISSUE_MM1(CI) { \
    const float* xb_ = x + ((size_t)b * IN_ + (CI) * 13 + r0_) * T_ + tg_; \
    g0 = tok ? xb_[0]       : 0.0f; \
    g1 = tok ? xb_[2  * T_] : 0.0f; \
    g2 = tok ? xb_[4  * T_] : 0.0f; \
    g3 = tok ? xb_[6  * T_] : 0.0f; \
    g4 = tok ? xb_[8  * T_] : 0.0f; \
    g5 = tok ? xb_[10 * T_] : 0.0f; \
    g6 = t6  ? xb_[12 * T_] : 0.0f; }

  ISSUE_MM1(0)
  for (int ci = 0; ci < 6; ++ci) {
    __syncthreads();
    {
      float* dst = &xs[r0_ * MSTR_ + c_];
      dst[0]          = g0;  dst[2  * MSTR_] = g1;
      dst[4  * MSTR_] = g2;  dst[6  * MSTR_] = g3;
      dst[8  * MSTR_] = g4;  dst[10 * MSTR_] = g5;
      if (r0_ == 0) dst[12 * MSTR_] = g6;
    }
    __syncthreads();
    if (ci < 5) ISSUE_MM1(ci + 1)     // loads fly under the compute below
    const int wbase0 = (2*p)     * 80 + ci * 13;
    const int wbase1 = (2*p + 1) * 80 + ci * 13;
#pragma unroll
    for (int i = 0; i < 13; ++i) {
      const float* xr = &xs[i * MSTR_ + 2 * q];
      MMROW2(xr, wd[wbase0 + i], wd[wbase1 + i])
    }
  }

  const size_t r0s = ((size_t)b * HID_ + 2*p) * T_;
  const size_t r1s = r0s + T_;
  const int tb = tcb + 2 * q;
  STORE2(r0s,  0, m00, m01)  STORE2(r0s, 64, m02, m03)
  STORE2(r1s,  0, m10, m11)  STORE2(r1s, 64, m12, m13)
}

// -------- fm: z2 = round32(W2 @ spike(FIR(z1))), per (b, tile) -------------
// Phase 1 = 4-output FIR (16h x 32 q8 = 512 tasks, 2 passes) -> spikes in
// LDS sf[16][128]; phase 2 = mm2 over this tile's 125 cols -> z2 global.
__global__ __launch_bounds__(256) void fm(
    const float* __restrict__ z1, const float* __restrict__ W2,
    float* __restrict__ z2)
{
  __shared__ float zf[HID_ * ZSTR_];  // 14,592 B
  __shared__ float sf[HID_ * 128];    //  8,192 B (spikes; cols >=125 unused)
  __shared__ float wf[OUT_ * HID_];   //  1,280 B
  __shared__ __align__(16) double eps_d[100];   // total ~24.9 KB

  const int tid  = threadIdx.x;
  const int b    = blockIdx.x >> 3;
  const int tile = blockIdx.x & 7;
  const int t0   = tile * TT_;

  init_eps_d(eps_d, tid);
  for (int idx = tid; idx < OUT_ * HID_; idx += 256)   // 320 > 256: strided
    wf[idx] = W2[idx];
  for (int idx = tid; idx < HID_ * ZSTR_; idx += 256) {
    const int cc = idx % ZSTR_;
    const int t  = t0 - 99 + cc;
    const int r  = idx / ZSTR_;
    zf[idx] = (cc < J_ && t >= 0) ? z1[((size_t)b * HID_ + r) * T_ + t] : 0.0f;
  }
  __syncthreads();

  // FIR + spike -> sf: 4 outputs/thread, 2 passes
#pragma unroll 1
  for (int task = tid; task < HID_ * 32; task += 256) {
    const int h = task >> 5, q8 = task & 31;
    const float* zrow4 = &zf[h * ZSTR_ + 4 * q8];
    double u0=0,u1=0,u2=0,u3=0;
    FIR4_BODY(zrow4)
    float* sd = &sf[h * 128 + 4 * q8];       // cols 125..127 garbage, unused
    sd[0] = ((float)u0 >= 1.0f) ? 1.0f : 0.0f;
    sd[1] = ((float)u1 >= 1.0f) ? 1.0f : 0.0f;
    sd[2] = ((float)u2 >= 1.0f) ? 1.0f : 0.0f;
    sd[3] = ((float)u3 >= 1.0f) ? 1.0f : 0.0f;
  }
  __syncthreads();

  { // mm2: 8 p-slots x 32 lanes; pg-loop covers 10 o-pairs
    const int p = tid >> 5;
    const int q = tid & 31;
#pragma unroll 1
    for (int pg = p; pg < 10; pg += 8) {
      double m00=0,m01=0,m02=0,m03=0,m10=0,m11=0,m12=0,m13=0;
      const int wb0 = (2*pg)     * HID_;
      const int wb1 = (2*pg + 1) * HID_;
#pragma unroll
      for (int i = 0; i < HID_; ++i) {
        const float* xr = &sf[i * 128 + 2 * q];
        MMROW2(xr, (double)wf[wb0 + i], (double)wf[wb1 + i])
      }
      const size_t r0s = ((size_t)b * OUT_ + 2*pg) * T_ + t0;
      const size_t r1s = r0s + T_;
      const int c0 = 2 * q;            // 0..62: pair always valid (<125)
      *(float2*)&z2[r0s + c0] = make_float2((float)m00, (float)m01);
      *(float2*)&z2[r1s + c0] = make_float2((float)m10, (float)m11);
      const int c1 = 64 + 2 * q;       // 64..126: guard vs TT_=125
      if (c1 + 1 < TT_) {
        *(float2*)&z2[r0s + c1] = make_float2((float)m02, (float)m03);
        *(float2*)&z2[r1s + c1] = make_float2((float)m12, (float)m13);
      } else if (c1 < TT_) {           // c1 == 124: scalar
        z2[r0s + c1] = (float)m02;
        z2[r1s + c1] = (float)m12;
      }
    }
  }
}

// -------- fir_g: sout = spike(FIR(zin)), R rows, 4 outputs/thread ----------
// Launch with 320 threads (R=20: 640 tasks = 2 passes).
// tile_fixed < 0: grid = B*8; else grid = B, single tile (in-place safe when
// tiles launched in DESCENDING order; tile k reads t < 125(k+1)).
__global__ __launch_bounds__(320) void fir_g(
    const float* __restrict__ zin, float* __restrict__ sout,
    int R, int tile_fixed)
{
  __shared__ float zf[OUT_ * ZSTR_];   // 18,240 B (R<=20)
  __shared__ __align__(16) double eps_d[100];

  const int tid  = threadIdx.x;
  const int nthr = blockDim.x;
  const int b    = (tile_fixed >= 0) ? (int)blockIdx.x : (int)(blockIdx.x >> 3);
  const int tile = (tile_fixed >= 0) ? tile_fixed      : (int)(blockIdx.x & 7);
  const int t0   = tile * TT_;

  init_eps_d(eps_d, tid);
  for (int idx = tid; idx < R * ZSTR_; idx += nthr) {
    const int cc = idx % ZSTR_;
    const int t  = t0 - 99 + cc;
    const int r  = idx / ZSTR_;
    zf[idx] = (cc < J_ && t >= 0) ? zin[((size_t)b * R + r) * T_ + t] : 0.0f;
  }
  __syncthreads();

#pragma unroll 1
  for (int task = tid; task < R * 32; task += nthr) {
    const int h = task >> 5, q8 = task & 31;
    const float* zrow4 = &zf[h * ZSTR_ + 4 * q8];
    double u0=0,u1=0,u2=0,u3=0;
    FIR4_BODY(zrow4)
    const int tb = 4 * q8;
    const size_t base = ((size_t)b * R + h) * T_ + t0 + tb;
    sout[base] = ((float)u0 >= 1.0f) ? 1.0f : 0.0f;     // tb <= 124 always
    if (tb + 1 < TT_) sout[base + 1] = ((float)u1 >= 1.0f) ? 1.0f : 0.0f;
    if (tb + 2 < TT_) sout[base + 2] = ((float)u2 >= 1.0f) ? 1.0f : 0.0f;
    if (tb + 3 < TT_) sout[base + 3] = ((float)u3 >= 1.0f) ? 1.0f : 0.0f;
  }
}

extern "C" void kernel_launch(void* const* d_in, const int* in_sizes, int n_in,
                              void* d_out, int out_size, void* d_ws, size_t ws_size,
                              hipStream_t stream) {
  const float* x  = (const float*)d_in[0];
  const float* W1 = (const float*)d_in[1];
  const float* W2 = (const float*)d_in[2];
  float* outp = (float*)d_out;
  float* base = (float*)d_ws;

  const size_t Z2E = (size_t)B_ * OUT_ * T_;   // 5.12M floats (20.5 MB)

  if (ws_size >= Z2E * sizeof(float)) {
    // z1 parks in d_out (16.4 MB <= 20.5 MB), z2 in ws; single fir2 launch.
    float* z1 = outp;
    float* z2 = base;
    mm1  <<<dim3(B_ * 8), dim3(256), 0, stream>>>(x,  W1, z1);
    fm   <<<dim3(B_ * 8), dim3(256), 0, stream>>>(z1, W2, z2);
    fir_g<<<dim3(B_ * 8), dim3(320), 0, stream>>>(z2, outp, OUT_, -1);
  } else {
    // z1 in ws, z2 in d_out, fir2 in-place with descending tiles (proven).
    float* z1 = base;
    float* z2 = outp;
    mm1<<<dim3(B_ * 8), dim3(256), 0, stream>>>(x,  W1, z1);
    fm <<<dim3(B_ * 8), dim3(256), 0, stream>>>(z1, W2, z2);
    for (int k = 7; k >= 0; --k)
      fir_g<<<dim3(B_), dim3(320), 0, stream>>>(z2, z2, OUT_, k);
  }
}